// Round 1
// baseline (487.813 us; speedup 1.0000x reference)
//
#include <hip/hip_runtime.h>
#include <hip/hip_bf16.h>
#include <stdint.h>

// ---------- types ----------
typedef _Float16 half8 __attribute__((ext_vector_type(8)));
typedef float floatx4 __attribute__((ext_vector_type(4)));

#define MFMA16(a, b, c) __builtin_amdgcn_mfma_f32_16x16x32_f16(a, b, c, 0, 0, 0)

// async global->LDS, 16B per lane, dest = wave-uniform base + lane*16
__device__ __forceinline__ void async_load16(const void* g, void* l) {
    __builtin_amdgcn_global_load_lds((__attribute__((address_space(1))) void*)(g),
                                     (__attribute__((address_space(3))) void*)(l),
                                     16, 0, 0);
}

// ---------- fp32 -> fp16 conversion (with optional scale) ----------
__global__ __launch_bounds__(256) void cvt_kernel(const float* __restrict__ in,
                                                  _Float16* __restrict__ out,
                                                  int n, float scale) {
    int i = (blockIdx.x * 256 + threadIdx.x) * 8;
    if (i >= n) return;
    float4 v0 = *(const float4*)(in + i);
    float4 v1 = *(const float4*)(in + i + 4);
    half8 h;
    h[0] = (_Float16)(v0.x * scale);
    h[1] = (_Float16)(v0.y * scale);
    h[2] = (_Float16)(v0.z * scale);
    h[3] = (_Float16)(v0.w * scale);
    h[4] = (_Float16)(v1.x * scale);
    h[5] = (_Float16)(v1.y * scale);
    h[6] = (_Float16)(v1.z * scale);
    h[7] = (_Float16)(v1.w * scale);
    *(half8*)(out + i) = h;
}

// ---------- C[m][n] = sum_k A[m][k] * B[n][k] ----------
// 128x128 tile, BK=32, 4 waves; double-buffered LDS, ONE barrier per k-chunk,
// prefetch issued after the barrier so it overlaps MFMA (drain happens next iter).
__global__ __launch_bounds__(256) void gemm_bt(const _Float16* __restrict__ A,
                                               const _Float16* __restrict__ B,
                                               _Float16* __restrict__ C,
                                               int M, int N, int K) {
    __shared__ _Float16 sA[2][128 * 32];   // 2 x 8 KB
    __shared__ _Float16 sB[2][128 * 32];
    const int tid  = threadIdx.x;
    const int lane = tid & 63;
    const int w    = tid >> 6;
    const int quad = lane >> 4;
    const int m16  = lane & 15;
    const int wm   = (w >> 1) << 6;
    const int wn   = (w & 1) << 6;
    const long row0 = (long)blockIdx.y * 128;
    const long col0 = (long)blockIdx.x * 128;

    floatx4 acc[4][4] = {};

    const _Float16* ga0 = A + (row0 + (tid >> 2)) * (long)K + (tid & 3) * 8;
    const _Float16* ga1 = ga0 + 64l * K;
    const _Float16* gb0 = B + (col0 + (tid >> 2)) * (long)K + (tid & 3) * 8;
    const _Float16* gb1 = gb0 + 64l * K;
    const int wchunk = (tid & 0xC0) * 16;   // wave-uniform byte base

    auto stage = [&](int bi, int kc) {
        char* lA = (char*)sA[bi] + wchunk;
        char* lB = (char*)sB[bi] + wchunk;
        async_load16(ga0 + kc, lA);
        async_load16(ga1 + kc, lA + 4096);
        async_load16(gb0 + kc, lB);
        async_load16(gb1 + kc, lB + 4096);
    };

    stage(0, 0);
    for (int kc = 0; kc < K; kc += 32) {
        const int bi = (kc >> 5) & 1;
        __syncthreads();                    // drains prefetch of THIS chunk
        if (kc + 32 < K) stage(bi ^ 1, kc + 32);
        half8 af[4], bf[4];
#pragma unroll
        for (int mt = 0; mt < 4; mt++)
            af[mt] = *(const half8*)(sA[bi] + (wm + mt * 16 + m16) * 32 + quad * 8);
#pragma unroll
        for (int nt = 0; nt < 4; nt++)
            bf[nt] = *(const half8*)(sB[bi] + (wn + nt * 16 + m16) * 32 + quad * 8);
#pragma unroll
        for (int mt = 0; mt < 4; mt++)
#pragma unroll
            for (int nt = 0; nt < 4; nt++)
                acc[mt][nt] = MFMA16(af[mt], bf[nt], acc[mt][nt]);
    }

#pragma unroll
    for (int mt = 0; mt < 4; mt++)
#pragma unroll
        for (int nt = 0; nt < 4; nt++)
#pragma unroll
            for (int reg = 0; reg < 4; reg++) {
                long r = row0 + wm + mt * 16 + quad * 4 + reg;
                long c = col0 + wn + nt * 16 + m16;
                C[r * N + c] = (_Float16)acc[mt][nt][reg];
            }
}

// ---------- attention kernel A: banded S = Q K^T -> softmax -> P (fp16) ----------
// block = 64 q-rows, 512 threads / 8 waves. Whole K band chunk staged in LDS.
// wave w: all 4 row-tiles x band-eighth (tiles t = w + 8i). acc[4][5] = 80 VGPR.
// qblk -> block mapping is XCD-chunked (qblk/32 == XCD id) so that pv_kernel's
// Pg reads hit the L2 of the XCD that wrote them.
__global__ __launch_bounds__(512) void qk_kernel(const _Float16* __restrict__ Qh,
                                                 const _Float16* __restrict__ Kh,
                                                 _Float16* __restrict__ Pg,
                                                 float* __restrict__ invSum) {
    const int S = 4096, D = 1024;
    __shared__ _Float16 sK[2][576 * 32];   // 2 x 36 KB
    __shared__ _Float16 sQ[2][64 * 32];    // 2 x 4 KB
    __shared__ float sMax[64][8];
    __shared__ float sSum[64][8];

    const int tid  = threadIdx.x;
    const int lane = tid & 63;
    const int w    = tid >> 6;
    const int quad = lane >> 4;
    const int c16  = lane & 15;
    // bijective XCD-chunk remap (256 % 8 == 0): xcd = bid&7 owns qblks [xcd*32, xcd*32+32)
    const int qblk = (blockIdx.x & 7) * 32 + (blockIdx.x >> 3);
    const int b    = qblk >> 6;
    const int q0   = (qblk & 63) << 6;

    int kstart = q0 - 256; if (kstart < 0) kstart = 0;   // multiple of 64
    int kend   = q0 + 320; if (kend > S) kend = S;       // multiple of 64
    const int L = kend - kstart;        // 320..576, multiple of 64
    const int ntiles = L >> 4;          // <= 36

    const int lrow = lane >> 2;         // 0..15
    const int lcol = (lane & 3) * 8;    // halves
    const _Float16* Kbase = Kh + ((long)(b * S + kstart) + lrow) * D + lcol;
    const _Float16* Qbase = Qh + ((long)(b * S + q0) + w * 16 + lrow) * D + lcol;

    auto stage = [&](int bi, int kc) {
#pragma unroll
        for (int j = 0; j < 5; j++) {
            int g = j * 8 + w;                       // 16-row group, wave-uniform
            if (g < ntiles)
                async_load16(Kbase + (long)g * 16 * D + kc, (char*)sK[bi] + g * 1024);
        }
        if (w < 4)
            async_load16(Qbase + kc, (char*)sQ[bi] + w * 1024);
    };

    floatx4 acc[4][5] = {};
    stage(0, 0);
    for (int kc = 0; kc < 1024; kc += 32) {
        const int bi = (kc >> 5) & 1;
        __syncthreads();
        if (kc + 32 < 1024) stage(bi ^ 1, kc + 32);
        half8 aQ[4];
#pragma unroll
        for (int mt = 0; mt < 4; mt++)
            aQ[mt] = *(const half8*)(sQ[bi] + (mt * 16 + c16) * 32 + quad * 8);
#pragma unroll
        for (int i = 0; i < 5; i++) {
            int t = w + i * 8;
            if (t < ntiles) {                        // wave-uniform
                half8 bK = *(const half8*)(sK[bi] + (t * 16 + c16) * 32 + quad * 8);
#pragma unroll
                for (int mt = 0; mt < 4; mt++)
                    acc[mt][i] = MFMA16(aQ[mt], bK, acc[mt][i]);
            }
        }
    }

    // band mask
#pragma unroll
    for (int i = 0; i < 5; i++) {
        int t = w + i * 8;
        if (t < ntiles) {
            int j = kstart + t * 16 + c16;
#pragma unroll
            for (int mt = 0; mt < 4; mt++)
#pragma unroll
                for (int r = 0; r < 4; r++) {
                    int qi = q0 + mt * 16 + quad * 4 + r;
                    int dd = qi - j; dd = dd < 0 ? -dd : dd;
                    if (dd > 256) acc[mt][i][r] = -1e30f;
                }
        }
    }
    // partial row max (this wave's band-eighth), reduce over the 16-lane col group
#pragma unroll
    for (int mt = 0; mt < 4; mt++)
#pragma unroll
        for (int r = 0; r < 4; r++) {
            float m = -1e30f;
#pragma unroll
            for (int i = 0; i < 5; i++)
                if (w + i * 8 < ntiles) m = fmaxf(m, acc[mt][i][r]);
#pragma unroll
            for (int off = 1; off < 16; off <<= 1) m = fmaxf(m, __shfl_xor(m, off, 64));
            if (c16 == 0) sMax[mt * 16 + quad * 4 + r][w] = m;
        }
    __syncthreads();
    if (tid < 64) {
        float fm = sMax[tid][0];
#pragma unroll
        for (int j = 1; j < 8; j++) fm = fmaxf(fm, sMax[tid][j]);
        sMax[tid][0] = fm;
    }
    __syncthreads();
    // exp, write P, partial sums
#pragma unroll
    for (int mt = 0; mt < 4; mt++)
#pragma unroll
        for (int r = 0; r < 4; r++) {
            int row = mt * 16 + quad * 4 + r;
            float fm = sMax[row][0];
            float s = 0.f;
#pragma unroll
            for (int i = 0; i < 5; i++) {
                int t = w + i * 8;
                if (t < ntiles) {
                    float e = __expf(acc[mt][i][r] - fm);   // masked -> 0
                    s += e;
                    Pg[(long)qblk * 36864 + row * 576 + t * 16 + c16] = (_Float16)e;
                }
            }
#pragma unroll
            for (int off = 1; off < 16; off <<= 1) s += __shfl_xor(s, off, 64);
            if (c16 == 0) sSum[row][w] = s;
        }
    __syncthreads();
    if (tid < 64) {
        float t = 0.f;
#pragma unroll
        for (int j = 0; j < 8; j++) t += sSum[tid][j];
        invSum[qblk * 64 + tid] = 1.f / t;
    }
}

// ---------- attention kernel B: O = P V (banded), from Vt [d][tok] ----------
// Direct-L2 streaming version: NO LDS staging, NO barriers in the main loop.
// Per-block working set (P tile 73 KB + Vt band slice ~1.1 MB, shared with
// neighboring q-blocks) is L2-resident, so LDS staging was pure overhead and
// the per-step __syncthreads forced a vmcnt(0) drain => latency-serialized.
// Each wave streams MFMA fragments straight from global (16B/lane, full 64B
// line use) with a register double-buffer; latency hidden by 16 independent
// waves/CU instead of barrier-locked steps.
// grid: 1024 linear blocks; XCD-chunked bijective remap, nb inner => the 4
// n-blocks of one qblk share an XCD (Pg fetched once per XCD), consecutive
// qblks follow (sliding Vt band stays in that XCD's L2).
__global__ __launch_bounds__(512, 4) void pv_kernel(const _Float16* __restrict__ Pg,
                                                    const float* __restrict__ invSum,
                                                    const _Float16* __restrict__ Vt,
                                                    float* __restrict__ out) {
    const int S = 4096, D = 1024, TOK = 16384;
    __shared__ float sInvB[64];

    const int tid  = threadIdx.x;
    const int lane = tid & 63;
    const int w    = tid >> 6;
    const int quad = lane >> 4;
    const int c16  = lane & 15;

    // bijective XCD-chunk remap (1024 % 8 == 0): xcd = bid&7 owns logical [xcd*128 ...)
    const int logical = (blockIdx.x & 7) * 128 + (blockIdx.x >> 3);
    const int qblk = logical >> 2;      // matches qk_kernel's qblk->XCD assignment
    const int n0   = (logical & 3) << 8;
    const int b    = qblk >> 6;
    const int q0   = (qblk & 63) << 6;

    int kstart = q0 - 256; if (kstart < 0) kstart = 0;
    int kend   = q0 + 320; if (kend > S) kend = S;
    const int nsteps = (kend - kstart) >> 5;   // 10..18, always even

    if (tid < 64) sInvB[tid] = invSum[qblk * 64 + tid];
    __syncthreads();                            // only barrier in the kernel

    const int wm = (w >> 2) * 32;               // wave: 32 q-rows x 64 d-cols
    const int wn = (w & 3) * 64;

    // A fragment: P rows (wm + mt*16 + c16), band cols (kc + quad*8); stride 576
    const _Float16* Ap = Pg + (long)qblk * 36864 + (wm + c16) * 576 + quad * 8;
    // B fragment: Vt rows (n0 + wn + nt*16 + c16), toks (kstart + kc + quad*8)
    const _Float16* Bp = Vt + (long)(n0 + wn + c16) * TOK + b * S + kstart + quad * 8;

    auto loadA = [&](half8* d, int kc) {
        d[0] = *(const half8*)(Ap + kc);
        d[1] = *(const half8*)(Ap + 16 * 576 + kc);
    };
    auto loadB = [&](half8* d, int kc) {
#pragma unroll
        for (int nt = 0; nt < 4; nt++)
            d[nt] = *(const half8*)(Bp + (long)nt * 16 * TOK + kc);
    };

    floatx4 acc[2][4] = {};
    half8 a0[2], a1[2], b0[4], b1[4];   // register double-buffer (static indices)

    loadA(a0, 0);
    loadB(b0, 0);
    for (int s = 0; s < nsteps; s += 2) {
        const int k1 = (s + 1) * 32;
        loadA(a1, k1);
        loadB(b1, k1);
#pragma unroll
        for (int mt = 0; mt < 2; mt++)
#pragma unroll
            for (int nt = 0; nt < 4; nt++)
                acc[mt][nt] = MFMA16(a0[mt], b0[nt], acc[mt][nt]);
        if (s + 2 < nsteps) {
            const int k2 = (s + 2) * 32;
            loadA(a0, k2);
            loadB(b0, k2);
        }
#pragma unroll
        for (int mt = 0; mt < 2; mt++)
#pragma unroll
            for (int nt = 0; nt < 4; nt++)
                acc[mt][nt] = MFMA16(a1[mt], b1[nt], acc[mt][nt]);
    }

#pragma unroll
    for (int mt = 0; mt < 2; mt++)
#pragma unroll
        for (int nt = 0; nt < 4; nt++)
#pragma unroll
            for (int reg = 0; reg < 4; reg++) {
                int row = wm + mt * 16 + quad * 4 + reg;
                int col = n0 + wn + nt * 16 + c16;
                out[(long)(b * S + q0 + row) * D + col] = acc[mt][nt][reg] * sInvB[row];
            }
}

extern "C" void kernel_launch(void* const* d_in, const int* in_sizes, int n_in,
                              void* d_out, int out_size, void* d_ws, size_t ws_size,
                              hipStream_t stream) {
    const float* X  = (const float*)d_in[0];
    const float* Y  = (const float*)d_in[1];
    const float* Wq = (const float*)d_in[2];
    const float* Wk = (const float*)d_in[3];
    const float* Wv = (const float*)d_in[4];
    float* out = (float*)d_out;

    const long NTOK = 16384, D = 1024;
    // fp16 workspace. Aliases (all stream-ordered safe):
    //   Kh = Yh   (Yh dead after Q-projection)
    //   Pg,invSum over Xh (Xh dead after V-projection; qk_kernel runs after)
    char* p = (char*)d_ws;
    _Float16* Xh  = (_Float16*)p; p += NTOK * D * 2;   // 32 MB
    _Float16* Yh  = (_Float16*)p; p += NTOK * D * 2;   // 32 MB (reused as Kh)
    _Float16* Wqh = (_Float16*)p; p += D * D * 2;      //  2 MB (pre-scaled by 1/32)
    _Float16* Wkh = (_Float16*)p; p += D * D * 2;
    _Float16* Wvh = (_Float16*)p; p += D * D * 2;
    _Float16* Qh  = (_Float16*)p; p += NTOK * D * 2;   // 32 MB
    _Float16* Vt  = (_Float16*)p; p += NTOK * D * 2;   // 32 MB  [D][NTOK]
    _Float16* Kh  = Yh;
    _Float16* Pg  = Xh;                                // 256*64*576*2 = 18.9 MB
    float* invSum = (float*)(Xh + 256l * 64 * 576);    // 64 KB, still inside Xh

    const int nT = (int)(NTOK * D);
    const int nW = (int)(D * D);
    cvt_kernel<<<nT / 2048, 256, 0, stream>>>(X, Xh, nT, 1.f);
    cvt_kernel<<<nT / 2048, 256, 0, stream>>>(Y, Yh, nT, 1.f);
    cvt_kernel<<<nW / 2048, 256, 0, stream>>>(Wq, Wqh, nW, 0.03125f);  // fold 1/sqrt(1024)
    cvt_kernel<<<nW / 2048, 256, 0, stream>>>(Wk, Wkh, nW, 1.f);
    cvt_kernel<<<nW / 2048, 256, 0, stream>>>(Wv, Wvh, nW, 1.f);

    // Q = Y Wq^T (scaled), K = X Wk^T, Vt = Wv X^T
    gemm_bt<<<dim3(1024 / 128, 16384 / 128), 256, 0, stream>>>(Yh, Wqh, Qh, 16384, 1024, 1024);
    gemm_bt<<<dim3(1024 / 128, 16384 / 128), 256, 0, stream>>>(Xh, Wkh, Kh, 16384, 1024, 1024);
    gemm_bt<<<dim3(16384 / 128, 1024 / 128), 256, 0, stream>>>(Wvh, Xh, Vt, 1024, 16384, 1024);

    qk_kernel<<<dim3(256), 512, 0, stream>>>(Qh, Kh, Pg, invSum);
    pv_kernel<<<dim3(4 * 256), 512, 0, stream>>>(Pg, invSum, Vt, out);
}

// Round 2
// 428.572 us; speedup vs baseline: 1.1382x; 1.1382x over previous
//
#include <hip/hip_runtime.h>
#include <hip/hip_bf16.h>
#include <stdint.h>

// ---------- types ----------
typedef _Float16 half8 __attribute__((ext_vector_type(8)));
typedef float floatx4 __attribute__((ext_vector_type(4)));

#define MFMA16(a, b, c) __builtin_amdgcn_mfma_f32_16x16x32_f16(a, b, c, 0, 0, 0)

// async global->LDS, 16B per lane, dest = wave-uniform base + lane*16
__device__ __forceinline__ void async_load16(const void* g, void* l) {
    __builtin_amdgcn_global_load_lds((__attribute__((address_space(1))) void*)(g),
                                     (__attribute__((address_space(3))) void*)(l),
                                     16, 0, 0);
}

// LDS XOR swizzle for [row][32]-fp16 tiles (4 x 16B granules per 64B row):
//   stored slot p of row r holds global granule p ^ ((r>>1)&3)
//   reader at quad q reads slot q ^ ((r>>1)&3)  -> global granule q
// 16 c16-lanes then span 8 distinct 4-bank groups (2-way = free) instead of 8-way.
// Staging lanes have r = base + (lane>>2), p = lane&3, so the pre-swizzled global
// granule is (lane&3) ^ ((lane>>3)&3) -- LDS dest stays linear (rule #21).

// ---------- fp32 -> fp16 conversion (with optional scale) ----------
__global__ __launch_bounds__(256) void cvt_kernel(const float* __restrict__ in,
                                                  _Float16* __restrict__ out,
                                                  int n, float scale) {
    int i = (blockIdx.x * 256 + threadIdx.x) * 8;
    if (i >= n) return;
    float4 v0 = *(const float4*)(in + i);
    float4 v1 = *(const float4*)(in + i + 4);
    half8 h;
    h[0] = (_Float16)(v0.x * scale);
    h[1] = (_Float16)(v0.y * scale);
    h[2] = (_Float16)(v0.z * scale);
    h[3] = (_Float16)(v0.w * scale);
    h[4] = (_Float16)(v1.x * scale);
    h[5] = (_Float16)(v1.y * scale);
    h[6] = (_Float16)(v1.z * scale);
    h[7] = (_Float16)(v1.w * scale);
    *(half8*)(out + i) = h;
}

// ---------- C[m][n] = sum_k A[m][k] * B[n][k] ----------
// 128x128 tile, BK=32, 4 waves; double-buffered LDS, ONE barrier per k-chunk.
__global__ __launch_bounds__(256) void gemm_bt(const _Float16* __restrict__ A,
                                               const _Float16* __restrict__ B,
                                               _Float16* __restrict__ C,
                                               int M, int N, int K) {
    __shared__ _Float16 sA[2][128 * 32];   // 2 x 8 KB
    __shared__ _Float16 sB[2][128 * 32];
    const int tid  = threadIdx.x;
    const int lane = tid & 63;
    const int w    = tid >> 6;
    const int quad = lane >> 4;
    const int m16  = lane & 15;
    const int wm   = (w >> 1) << 6;
    const int wn   = (w & 1) << 6;
    const long row0 = (long)blockIdx.y * 128;
    const long col0 = (long)blockIdx.x * 128;

    floatx4 acc[4][4] = {};

    const _Float16* ga0 = A + (row0 + (tid >> 2)) * (long)K + (tid & 3) * 8;
    const _Float16* ga1 = ga0 + 64l * K;
    const _Float16* gb0 = B + (col0 + (tid >> 2)) * (long)K + (tid & 3) * 8;
    const _Float16* gb1 = gb0 + 64l * K;
    const int wchunk = (tid & 0xC0) * 16;   // wave-uniform byte base

    auto stage = [&](int bi, int kc) {
        char* lA = (char*)sA[bi] + wchunk;
        char* lB = (char*)sB[bi] + wchunk;
        async_load16(ga0 + kc, lA);
        async_load16(ga1 + kc, lA + 4096);
        async_load16(gb0 + kc, lB);
        async_load16(gb1 + kc, lB + 4096);
    };

    stage(0, 0);
    for (int kc = 0; kc < K; kc += 32) {
        const int bi = (kc >> 5) & 1;
        __syncthreads();                    // drains prefetch of THIS chunk
        if (kc + 32 < K) stage(bi ^ 1, kc + 32);
        half8 af[4], bf[4];
#pragma unroll
        for (int mt = 0; mt < 4; mt++)
            af[mt] = *(const half8*)(sA[bi] + (wm + mt * 16 + m16) * 32 + quad * 8);
#pragma unroll
        for (int nt = 0; nt < 4; nt++)
            bf[nt] = *(const half8*)(sB[bi] + (wn + nt * 16 + m16) * 32 + quad * 8);
#pragma unroll
        for (int mt = 0; mt < 4; mt++)
#pragma unroll
            for (int nt = 0; nt < 4; nt++)
                acc[mt][nt] = MFMA16(af[mt], bf[nt], acc[mt][nt]);
    }

#pragma unroll
    for (int mt = 0; mt < 4; mt++)
#pragma unroll
        for (int nt = 0; nt < 4; nt++)
#pragma unroll
            for (int reg = 0; reg < 4; reg++) {
                long r = row0 + wm + mt * 16 + quad * 4 + reg;
                long c = col0 + wn + nt * 16 + m16;
                C[r * N + c] = (_Float16)acc[mt][nt][reg];
            }
}

// ---------- attention kernel A: banded S = Q K^T -> softmax -> P (fp16) ----------
// block = 64 q-rows, 512 threads / 8 waves. Whole K band chunk staged in LDS.
// XCD-chunked qblk remap (qblk/32 == XCD) pairs with pv's remap for L2 locality.
// LDS tiles use the XOR swizzle above (conflict-free ds_read_b128).
__global__ __launch_bounds__(512) void qk_kernel(const _Float16* __restrict__ Qh,
                                                 const _Float16* __restrict__ Kh,
                                                 _Float16* __restrict__ Pg,
                                                 float* __restrict__ invSum) {
    const int S = 4096, D = 1024;
    __shared__ _Float16 sK[2][576 * 32];   // 2 x 36 KB
    __shared__ _Float16 sQ[2][64 * 32];    // 2 x 4 KB
    __shared__ float sMax[64][8];
    __shared__ float sSum[64][8];

    const int tid  = threadIdx.x;
    const int lane = tid & 63;
    const int w    = tid >> 6;
    const int quad = lane >> 4;
    const int c16  = lane & 15;
    // bijective XCD-chunk remap (256 % 8 == 0)
    const int qblk = (blockIdx.x & 7) * 32 + (blockIdx.x >> 3);
    const int b    = qblk >> 6;
    const int q0   = (qblk & 63) << 6;

    int kstart = q0 - 256; if (kstart < 0) kstart = 0;   // multiple of 64
    int kend   = q0 + 320; if (kend > S) kend = S;       // multiple of 64
    const int L = kend - kstart;        // 320..576, multiple of 64
    const int ntiles = L >> 4;          // <= 36

    const int lrow = lane >> 2;                          // 0..15
    const int swz  = ((lane & 3) ^ ((lane >> 3) & 3)) * 8;  // pre-swizzled granule
    const _Float16* Kbase = Kh + ((long)(b * S + kstart) + lrow) * D + swz;
    const _Float16* Qbase = Qh + ((long)(b * S + q0) + w * 16 + lrow) * D + swz;

    auto stage = [&](int bi, int kc) {
#pragma unroll
        for (int j = 0; j < 5; j++) {
            int g = j * 8 + w;                       // 16-row group, wave-uniform
            if (g < ntiles)
                async_load16(Kbase + (long)g * 16 * D + kc, (char*)sK[bi] + g * 1024);
        }
        if (w < 4)
            async_load16(Qbase + kc, (char*)sQ[bi] + w * 1024);
    };

    const int rswz = ((c16 >> 1) & 3);   // == (row>>1)&3 for row = 16*base + c16

    floatx4 acc[4][5] = {};
    stage(0, 0);
    for (int kc = 0; kc < 1024; kc += 32) {
        const int bi = (kc >> 5) & 1;
        __syncthreads();
        if (kc + 32 < 1024) stage(bi ^ 1, kc + 32);
        half8 aQ[4];
#pragma unroll
        for (int mt = 0; mt < 4; mt++)
            aQ[mt] = *(const half8*)(sQ[bi] + (mt * 16 + c16) * 32 + (quad ^ rswz) * 8);
#pragma unroll
        for (int i = 0; i < 5; i++) {
            int t = w + i * 8;
            if (t < ntiles) {                        // wave-uniform
                half8 bK = *(const half8*)(sK[bi] + (t * 16 + c16) * 32 + (quad ^ rswz) * 8);
#pragma unroll
                for (int mt = 0; mt < 4; mt++)
                    acc[mt][i] = MFMA16(aQ[mt], bK, acc[mt][i]);
            }
        }
    }

    // band mask
#pragma unroll
    for (int i = 0; i < 5; i++) {
        int t = w + i * 8;
        if (t < ntiles) {
            int j = kstart + t * 16 + c16;
#pragma unroll
            for (int mt = 0; mt < 4; mt++)
#pragma unroll
                for (int r = 0; r < 4; r++) {
                    int qi = q0 + mt * 16 + quad * 4 + r;
                    int dd = qi - j; dd = dd < 0 ? -dd : dd;
                    if (dd > 256) acc[mt][i][r] = -1e30f;
                }
        }
    }
    // partial row max (this wave's band-eighth), reduce over the 16-lane col group
#pragma unroll
    for (int mt = 0; mt < 4; mt++)
#pragma unroll
        for (int r = 0; r < 4; r++) {
            float m = -1e30f;
#pragma unroll
            for (int i = 0; i < 5; i++)
                if (w + i * 8 < ntiles) m = fmaxf(m, acc[mt][i][r]);
#pragma unroll
            for (int off = 1; off < 16; off <<= 1) m = fmaxf(m, __shfl_xor(m, off, 64));
            if (c16 == 0) sMax[mt * 16 + quad * 4 + r][w] = m;
        }
    __syncthreads();
    if (tid < 64) {
        float fm = sMax[tid][0];
#pragma unroll
        for (int j = 1; j < 8; j++) fm = fmaxf(fm, sMax[tid][j]);
        sMax[tid][0] = fm;
    }
    __syncthreads();
    // exp, write P, partial sums
#pragma unroll
    for (int mt = 0; mt < 4; mt++)
#pragma unroll
        for (int r = 0; r < 4; r++) {
            int row = mt * 16 + quad * 4 + r;
            float fm = sMax[row][0];
            float s = 0.f;
#pragma unroll
            for (int i = 0; i < 5; i++) {
                int t = w + i * 8;
                if (t < ntiles) {
                    float e = __expf(acc[mt][i][r] - fm);   // masked -> 0
                    s += e;
                    Pg[(long)qblk * 36864 + row * 576 + t * 16 + c16] = (_Float16)e;
                }
            }
#pragma unroll
            for (int off = 1; off < 16; off <<= 1) s += __shfl_xor(s, off, 64);
            if (c16 == 0) sSum[row][w] = s;
        }
    __syncthreads();
    if (tid < 64) {
        float t = 0.f;
#pragma unroll
        for (int j = 0; j < 8; j++) t += sSum[tid][j];
        invSum[qblk * 64 + tid] = 1.f / t;
    }
}

// ---------- attention kernel B: O = P V (banded), from Vt [d][tok] ----------
// LDS-staged 2-phase structure (Round-0, proven) + XCD-chunked remap (proven
// -138 MB HBM fetch: Pg/Vt become L2 hits) + XOR-swizzled LDS (kills the 8-way
// ds_read_b128 bank conflict that sat on the per-step critical path).
// grid: 1024 linear blocks; remap puts the 4 n-blocks of one qblk plus 32
// consecutive qblks on one XCD (matches qk's qblk->XCD map).
// LDS = 40 KB -> 3 blocks/CU (barrier-offset overlap across blocks).
__global__ __launch_bounds__(512) void pv_kernel(const _Float16* __restrict__ Pg,
                                                 const float* __restrict__ invSum,
                                                 const _Float16* __restrict__ Vt,
                                                 float* __restrict__ out) {
    const int S = 4096, D = 1024, TOK = 16384;
    __shared__ _Float16 sA[2][64 * 32];    // 2 x 4 KB
    __shared__ _Float16 sB[2][256 * 32];   // 2 x 16 KB

    const int tid  = threadIdx.x;
    const int lane = tid & 63;
    const int w    = tid >> 6;
    const int quad = lane >> 4;
    const int c16  = lane & 15;

    // bijective XCD-chunk remap (1024 % 8 == 0); n-block inner, qblk outer
    const int logical = (blockIdx.x & 7) * 128 + (blockIdx.x >> 3);
    const int qblk = logical >> 2;      // qblk/32 == XCD id, matches qk_kernel
    const int n0   = (logical & 3) << 8;
    const int b    = qblk >> 6;
    const int q0   = (qblk & 63) << 6;

    int kstart = q0 - 256; if (kstart < 0) kstart = 0;
    int kend   = q0 + 320; if (kend > S) kend = S;
    const int nsteps = (kend - kstart) >> 5;   // 10..18, even

    const int lrow = lane >> 2;
    const int swz  = ((lane & 3) ^ ((lane >> 3) & 3)) * 8;  // pre-swizzled granule
    const _Float16* Abase = Pg + (long)qblk * 36864 + (w * 16 + lrow) * 576 + swz;
    const _Float16* Bbase = Vt + (long)(n0 + lrow) * TOK + b * S + kstart + swz;

    auto stage = [&](int bi, int kc) {
        if (w < 4)
            async_load16(Abase + kc, (char*)sA[bi] + w * 1024);
#pragma unroll
        for (int j = 0; j < 2; j++) {
            int g = j * 8 + w;
            async_load16(Bbase + (long)g * 16 * TOK + kc, (char*)sB[bi] + g * 1024);
        }
    };

    const int wm = (w >> 2) * 32;
    const int wn = (w & 3) * 64;
    const int rswz = ((c16 >> 1) & 3);   // == (row>>1)&3 for row = 16*base + c16
    floatx4 acc[2][4] = {};

    stage(0, 0);
    for (int s = 0; s < nsteps; s++) {
        const int bi = s & 1;
        __syncthreads();
        if (s + 1 < nsteps) stage(bi ^ 1, (s + 1) * 32);
        half8 aA[2], bB[4];
#pragma unroll
        for (int mt = 0; mt < 2; mt++)
            aA[mt] = *(const half8*)(sA[bi] + (wm + mt * 16 + c16) * 32 + (quad ^ rswz) * 8);
#pragma unroll
        for (int nt = 0; nt < 4; nt++)
            bB[nt] = *(const half8*)(sB[bi] + (wn + nt * 16 + c16) * 32 + (quad ^ rswz) * 8);
#pragma unroll
        for (int mt = 0; mt < 2; mt++)
#pragma unroll
            for (int nt = 0; nt < 4; nt++)
                acc[mt][nt] = MFMA16(aA[mt], bB[nt], acc[mt][nt]);
    }

    const float* isB = invSum + qblk * 64;
#pragma unroll
    for (int mt = 0; mt < 2; mt++)
#pragma unroll
        for (int nt = 0; nt < 4; nt++)
#pragma unroll
            for (int reg = 0; reg < 4; reg++) {
                int row = wm + mt * 16 + quad * 4 + reg;
                int col = n0 + wn + nt * 16 + c16;
                out[(long)(b * S + q0 + row) * D + col] = acc[mt][nt][reg] * isB[row];
            }
}

extern "C" void kernel_launch(void* const* d_in, const int* in_sizes, int n_in,
                              void* d_out, int out_size, void* d_ws, size_t ws_size,
                              hipStream_t stream) {
    const float* X  = (const float*)d_in[0];
    const float* Y  = (const float*)d_in[1];
    const float* Wq = (const float*)d_in[2];
    const float* Wk = (const float*)d_in[3];
    const float* Wv = (const float*)d_in[4];
    float* out = (float*)d_out;

    const long NTOK = 16384, D = 1024;
    // fp16 workspace. Aliases (all stream-ordered safe):
    //   Kh = Yh   (Yh dead after Q-projection)
    //   Pg,invSum over Xh (Xh dead after V-projection; qk_kernel runs after)
    char* p = (char*)d_ws;
    _Float16* Xh  = (_Float16*)p; p += NTOK * D * 2;   // 32 MB
    _Float16* Yh  = (_Float16*)p; p += NTOK * D * 2;   // 32 MB (reused as Kh)
    _Float16* Wqh = (_Float16*)p; p += D * D * 2;      //  2 MB (pre-scaled by 1/32)
    _Float16* Wkh = (_Float16*)p; p += D * D * 2;
    _Float16* Wvh = (_Float16*)p; p += D * D * 2;
    _Float16* Qh  = (_Float16*)p; p += NTOK * D * 2;   // 32 MB
    _Float16* Vt  = (_Float16*)p; p += NTOK * D * 2;   // 32 MB  [D][NTOK]
    _Float16* Kh  = Yh;
    _Float16* Pg  = Xh;                                // 256*64*576*2 = 18.9 MB
    float* invSum = (float*)(Xh + 256l * 64 * 576);    // 64 KB, still inside Xh

    const int nT = (int)(NTOK * D);
    const int nW = (int)(D * D);
    cvt_kernel<<<nT / 2048, 256, 0, stream>>>(X, Xh, nT, 1.f);
    cvt_kernel<<<nT / 2048, 256, 0, stream>>>(Y, Yh, nT, 1.f);
    cvt_kernel<<<nW / 2048, 256, 0, stream>>>(Wq, Wqh, nW, 0.03125f);  // fold 1/sqrt(1024)
    cvt_kernel<<<nW / 2048, 256, 0, stream>>>(Wk, Wkh, nW, 1.f);
    cvt_kernel<<<nW / 2048, 256, 0, stream>>>(Wv, Wvh, nW, 1.f);

    // Q = Y Wq^T (scaled), K = X Wk^T, Vt = Wv X^T
    gemm_bt<<<dim3(1024 / 128, 16384 / 128), 256, 0, stream>>>(Yh, Wqh, Qh, 16384, 1024, 1024);
    gemm_bt<<<dim3(1024 / 128, 16384 / 128), 256, 0, stream>>>(Xh, Wkh, Kh, 16384, 1024, 1024);
    gemm_bt<<<dim3(16384 / 128, 1024 / 128), 256, 0, stream>>>(Wvh, Xh, Vt, 1024, 16384, 1024);

    qk_kernel<<<dim3(256), 512, 0, stream>>>(Qh, Kh, Pg, invSum);
    pv_kernel<<<dim3(4 * 256), 512, 0, stream>>>(Pg, invSum, Vt, out);
}

// Round 3
// 411.776 us; speedup vs baseline: 1.1847x; 1.0408x over previous
//
#include <hip/hip_runtime.h>
#include <hip/hip_bf16.h>
#include <stdint.h>

// ---------- types ----------
typedef _Float16 half8 __attribute__((ext_vector_type(8)));
typedef float floatx4 __attribute__((ext_vector_type(4)));

#define MFMA16(a, b, c) __builtin_amdgcn_mfma_f32_16x16x32_f16(a, b, c, 0, 0, 0)

// async global->LDS, 16B per lane, dest = wave-uniform base + lane*16
__device__ __forceinline__ void async_load16(const void* g, void* l) {
    __builtin_amdgcn_global_load_lds((__attribute__((address_space(1))) void*)(g),
                                     (__attribute__((address_space(3))) void*)(l),
                                     16, 0, 0);
}

// LDS XOR swizzle for [row][32]-fp16 tiles (4 x 16B granules per 64B row):
//   stored slot p of row r holds global granule p ^ ((r>>1)&3)
//   reader at quad q reads slot q ^ ((r>>1)&3)  -> global granule q
// 16 row-lanes then span all 32 banks at 2-way (free) instead of 8-way.
// Staging lanes have r = base + (lane>>2), p = lane&3, so the pre-swizzled global
// granule is (lane&3) ^ ((lane>>3)&3) -- LDS dest stays linear (rule #21).

// ---------- fp32 -> fp16 conversion (with optional scale) ----------
__global__ __launch_bounds__(256) void cvt_kernel(const float* __restrict__ in,
                                                  _Float16* __restrict__ out,
                                                  int n, float scale) {
    int i = (blockIdx.x * 256 + threadIdx.x) * 8;
    if (i >= n) return;
    float4 v0 = *(const float4*)(in + i);
    float4 v1 = *(const float4*)(in + i + 4);
    half8 h;
    h[0] = (_Float16)(v0.x * scale);
    h[1] = (_Float16)(v0.y * scale);
    h[2] = (_Float16)(v0.z * scale);
    h[3] = (_Float16)(v0.w * scale);
    h[4] = (_Float16)(v1.x * scale);
    h[5] = (_Float16)(v1.y * scale);
    h[6] = (_Float16)(v1.z * scale);
    h[7] = (_Float16)(v1.w * scale);
    *(half8*)(out + i) = h;
}

// ---------- C[m][n] = sum_k A[m][k] * B[n][k] ----------
// 128x128 tile, BK=32, 4 waves; double-buffered LDS, ONE barrier per k-chunk.
// XCD-chunked block remap: each XCD gets a contiguous strip of the large grid
// dim x the full small dim (working set ~6 MB/XCD -> staging loads L2-hit,
// shrinking the per-step vmcnt drain). LDS XOR swizzle kills the 8-way
// ds_read_b128 bank conflict (4.2M/dispatch measured).
__global__ __launch_bounds__(256) void gemm_bt(const _Float16* __restrict__ A,
                                               const _Float16* __restrict__ B,
                                               _Float16* __restrict__ C,
                                               int M, int N, int K) {
    __shared__ _Float16 sA[2][128 * 32];   // 2 x 8 KB
    __shared__ _Float16 sB[2][128 * 32];
    const int tid  = threadIdx.x;
    const int lane = tid & 63;
    const int w    = tid >> 6;
    const int quad = lane >> 4;
    const int m16  = lane & 15;
    const int wm   = (w >> 1) << 6;
    const int wn   = (w & 1) << 6;

    // bijective XCD-chunk remap (total % 8 == 0). Fast axis inside a chunk is
    // the SMALL grid dim, so each XCD covers full small-dim strips of the
    // large dim (max panel reuse inside one L2).
    const int gx = gridDim.x, gy = gridDim.y;
    const int total = gx * gy;
    const int id = blockIdx.y * gx + blockIdx.x;
    const int logical = (id & 7) * (total >> 3) + (id >> 3);
    int bx, by;
    if (gx <= gy) { bx = logical % gx; by = logical / gx; }
    else          { by = logical % gy; bx = logical / gy; }
    const long row0 = (long)by * 128;
    const long col0 = (long)bx * 128;

    floatx4 acc[4][4] = {};

    const int swz = ((tid & 3) ^ ((tid >> 3) & 3)) * 8;   // pre-swizzled granule
    const _Float16* ga0 = A + (row0 + (tid >> 2)) * (long)K + swz;
    const _Float16* ga1 = ga0 + 64l * K;
    const _Float16* gb0 = B + (col0 + (tid >> 2)) * (long)K + swz;
    const _Float16* gb1 = gb0 + 64l * K;
    const int wchunk = (tid & 0xC0) * 16;   // wave-uniform byte base

    auto stage = [&](int bi, int kc) {
        char* lA = (char*)sA[bi] + wchunk;
        char* lB = (char*)sB[bi] + wchunk;
        async_load16(ga0 + kc, lA);
        async_load16(ga1 + kc, lA + 4096);
        async_load16(gb0 + kc, lB);
        async_load16(gb1 + kc, lB + 4096);
    };

    const int rswz = (m16 >> 1) & 3;        // == (row>>1)&3 for row = base16 + m16

    stage(0, 0);
    for (int kc = 0; kc < K; kc += 32) {
        const int bi = (kc >> 5) & 1;
        __syncthreads();                    // drains prefetch of THIS chunk
        if (kc + 32 < K) stage(bi ^ 1, kc + 32);
        half8 af[4], bf[4];
#pragma unroll
        for (int mt = 0; mt < 4; mt++)
            af[mt] = *(const half8*)(sA[bi] + (wm + mt * 16 + m16) * 32 + (quad ^ rswz) * 8);
#pragma unroll
        for (int nt = 0; nt < 4; nt++)
            bf[nt] = *(const half8*)(sB[bi] + (wn + nt * 16 + m16) * 32 + (quad ^ rswz) * 8);
#pragma unroll
        for (int mt = 0; mt < 4; mt++)
#pragma unroll
            for (int nt = 0; nt < 4; nt++)
                acc[mt][nt] = MFMA16(af[mt], bf[nt], acc[mt][nt]);
    }

#pragma unroll
    for (int mt = 0; mt < 4; mt++)
#pragma unroll
        for (int nt = 0; nt < 4; nt++)
#pragma unroll
            for (int reg = 0; reg < 4; reg++) {
                long r = row0 + wm + mt * 16 + quad * 4 + reg;
                long c = col0 + wn + nt * 16 + m16;
                C[r * N + c] = (_Float16)acc[mt][nt][reg];
            }
}

// ---------- attention kernel A: banded S = Q K^T -> softmax -> P (fp16) ----------
// block = 64 q-rows, 512 threads / 8 waves. Whole K band chunk staged in LDS.
// XCD-chunked qblk remap (qblk/32 == XCD) pairs with pv's remap for L2 locality.
// LDS tiles use the XOR swizzle above (conflict-free ds_read_b128).
__global__ __launch_bounds__(512) void qk_kernel(const _Float16* __restrict__ Qh,
                                                 const _Float16* __restrict__ Kh,
                                                 _Float16* __restrict__ Pg,
                                                 float* __restrict__ invSum) {
    const int S = 4096, D = 1024;
    __shared__ _Float16 sK[2][576 * 32];   // 2 x 36 KB
    __shared__ _Float16 sQ[2][64 * 32];    // 2 x 4 KB
    __shared__ float sMax[64][8];
    __shared__ float sSum[64][8];

    const int tid  = threadIdx.x;
    const int lane = tid & 63;
    const int w    = tid >> 6;
    const int quad = lane >> 4;
    const int c16  = lane & 15;
    // bijective XCD-chunk remap (256 % 8 == 0)
    const int qblk = (blockIdx.x & 7) * 32 + (blockIdx.x >> 3);
    const int b    = qblk >> 6;
    const int q0   = (qblk & 63) << 6;

    int kstart = q0 - 256; if (kstart < 0) kstart = 0;   // multiple of 64
    int kend   = q0 + 320; if (kend > S) kend = S;       // multiple of 64
    const int L = kend - kstart;        // 320..576, multiple of 64
    const int ntiles = L >> 4;          // <= 36

    const int lrow = lane >> 2;                          // 0..15
    const int swz  = ((lane & 3) ^ ((lane >> 3) & 3)) * 8;  // pre-swizzled granule
    const _Float16* Kbase = Kh + ((long)(b * S + kstart) + lrow) * D + swz;
    const _Float16* Qbase = Qh + ((long)(b * S + q0) + w * 16 + lrow) * D + swz;

    auto stage = [&](int bi, int kc) {
#pragma unroll
        for (int j = 0; j < 5; j++) {
            int g = j * 8 + w;                       // 16-row group, wave-uniform
            if (g < ntiles)
                async_load16(Kbase + (long)g * 16 * D + kc, (char*)sK[bi] + g * 1024);
        }
        if (w < 4)
            async_load16(Qbase + kc, (char*)sQ[bi] + w * 1024);
    };

    const int rswz = ((c16 >> 1) & 3);   // == (row>>1)&3 for row = 16*base + c16

    floatx4 acc[4][5] = {};
    stage(0, 0);
    for (int kc = 0; kc < 1024; kc += 32) {
        const int bi = (kc >> 5) & 1;
        __syncthreads();
        if (kc + 32 < 1024) stage(bi ^ 1, kc + 32);
        half8 aQ[4];
#pragma unroll
        for (int mt = 0; mt < 4; mt++)
            aQ[mt] = *(const half8*)(sQ[bi] + (mt * 16 + c16) * 32 + (quad ^ rswz) * 8);
#pragma unroll
        for (int i = 0; i < 5; i++) {
            int t = w + i * 8;
            if (t < ntiles) {                        // wave-uniform
                half8 bK = *(const half8*)(sK[bi] + (t * 16 + c16) * 32 + (quad ^ rswz) * 8);
#pragma unroll
                for (int mt = 0; mt < 4; mt++)
                    acc[mt][i] = MFMA16(aQ[mt], bK, acc[mt][i]);
            }
        }
    }

    // band mask
#pragma unroll
    for (int i = 0; i < 5; i++) {
        int t = w + i * 8;
        if (t < ntiles) {
            int j = kstart + t * 16 + c16;
#pragma unroll
            for (int mt = 0; mt < 4; mt++)
#pragma unroll
                for (int r = 0; r < 4; r++) {
                    int qi = q0 + mt * 16 + quad * 4 + r;
                    int dd = qi - j; dd = dd < 0 ? -dd : dd;
                    if (dd > 256) acc[mt][i][r] = -1e30f;
                }
        }
    }
    // partial row max (this wave's band-eighth), reduce over the 16-lane col group
#pragma unroll
    for (int mt = 0; mt < 4; mt++)
#pragma unroll
        for (int r = 0; r < 4; r++) {
            float m = -1e30f;
#pragma unroll
            for (int i = 0; i < 5; i++)
                if (w + i * 8 < ntiles) m = fmaxf(m, acc[mt][i][r]);
#pragma unroll
            for (int off = 1; off < 16; off <<= 1) m = fmaxf(m, __shfl_xor(m, off, 64));
            if (c16 == 0) sMax[mt * 16 + quad * 4 + r][w] = m;
        }
    __syncthreads();
    if (tid < 64) {
        float fm = sMax[tid][0];
#pragma unroll
        for (int j = 1; j < 8; j++) fm = fmaxf(fm, sMax[tid][j]);
        sMax[tid][0] = fm;
    }
    __syncthreads();
    // exp, write P, partial sums
#pragma unroll
    for (int mt = 0; mt < 4; mt++)
#pragma unroll
        for (int r = 0; r < 4; r++) {
            int row = mt * 16 + quad * 4 + r;
            float fm = sMax[row][0];
            float s = 0.f;
#pragma unroll
            for (int i = 0; i < 5; i++) {
                int t = w + i * 8;
                if (t < ntiles) {
                    float e = __expf(acc[mt][i][r] - fm);   // masked -> 0
                    s += e;
                    Pg[(long)qblk * 36864 + row * 576 + t * 16 + c16] = (_Float16)e;
                }
            }
#pragma unroll
            for (int off = 1; off < 16; off <<= 1) s += __shfl_xor(s, off, 64);
            if (c16 == 0) sSum[row][w] = s;
        }
    __syncthreads();
    if (tid < 64) {
        float t = 0.f;
#pragma unroll
        for (int j = 0; j < 8; j++) t += sSum[tid][j];
        invSum[qblk * 64 + tid] = 1.f / t;
    }
}

// ---------- attention kernel B: O = P V (banded), from Vt [d][tok] ----------
// LDS-staged 2-phase structure + XCD-chunked remap (Pg/Vt L2-resident) +
// XOR-swizzled LDS (conflict-free ds_read_b128).
__global__ __launch_bounds__(512) void pv_kernel(const _Float16* __restrict__ Pg,
                                                 const float* __restrict__ invSum,
                                                 const _Float16* __restrict__ Vt,
                                                 float* __restrict__ out) {
    const int S = 4096, D = 1024, TOK = 16384;
    __shared__ _Float16 sA[2][64 * 32];    // 2 x 4 KB
    __shared__ _Float16 sB[2][256 * 32];   // 2 x 16 KB

    const int tid  = threadIdx.x;
    const int lane = tid & 63;
    const int w    = tid >> 6;
    const int quad = lane >> 4;
    const int c16  = lane & 15;

    // bijective XCD-chunk remap (1024 % 8 == 0); n-block inner, qblk outer
    const int logical = (blockIdx.x & 7) * 128 + (blockIdx.x >> 3);
    const int qblk = logical >> 2;      // qblk/32 == XCD id, matches qk_kernel
    const int n0   = (logical & 3) << 8;
    const int b    = qblk >> 6;
    const int q0   = (qblk & 63) << 6;

    int kstart = q0 - 256; if (kstart < 0) kstart = 0;
    int kend   = q0 + 320; if (kend > S) kend = S;
    const int nsteps = (kend - kstart) >> 5;   // 10..18, even

    const int lrow = lane >> 2;
    const int swz  = ((lane & 3) ^ ((lane >> 3) & 3)) * 8;  // pre-swizzled granule
    const _Float16* Abase = Pg + (long)qblk * 36864 + (w * 16 + lrow) * 576 + swz;
    const _Float16* Bbase = Vt + (long)(n0 + lrow) * TOK + b * S + kstart + swz;

    auto stage = [&](int bi, int kc) {
        if (w < 4)
            async_load16(Abase + kc, (char*)sA[bi] + w * 1024);
#pragma unroll
        for (int j = 0; j < 2; j++) {
            int g = j * 8 + w;
            async_load16(Bbase + (long)g * 16 * TOK + kc, (char*)sB[bi] + g * 1024);
        }
    };

    const int wm = (w >> 2) * 32;
    const int wn = (w & 3) * 64;
    const int rswz = ((c16 >> 1) & 3);   // == (row>>1)&3 for row = 16*base + c16
    floatx4 acc[2][4] = {};

    stage(0, 0);
    for (int s = 0; s < nsteps; s++) {
        const int bi = s & 1;
        __syncthreads();
        if (s + 1 < nsteps) stage(bi ^ 1, (s + 1) * 32);
        half8 aA[2], bB[4];
#pragma unroll
        for (int mt = 0; mt < 2; mt++)
            aA[mt] = *(const half8*)(sA[bi] + (wm + mt * 16 + c16) * 32 + (quad ^ rswz) * 8);
#pragma unroll
        for (int nt = 0; nt < 4; nt++)
            bB[nt] = *(const half8*)(sB[bi] + (wn + nt * 16 + c16) * 32 + (quad ^ rswz) * 8);
#pragma unroll
        for (int mt = 0; mt < 2; mt++)
#pragma unroll
            for (int nt = 0; nt < 4; nt++)
                acc[mt][nt] = MFMA16(aA[mt], bB[nt], acc[mt][nt]);
    }

    const float* isB = invSum + qblk * 64;
#pragma unroll
    for (int mt = 0; mt < 2; mt++)
#pragma unroll
        for (int nt = 0; nt < 4; nt++)
#pragma unroll
            for (int reg = 0; reg < 4; reg++) {
                int row = wm + mt * 16 + quad * 4 + reg;
                int col = n0 + wn + nt * 16 + c16;
                out[(long)(b * S + q0 + row) * D + col] = acc[mt][nt][reg] * isB[row];
            }
}

extern "C" void kernel_launch(void* const* d_in, const int* in_sizes, int n_in,
                              void* d_out, int out_size, void* d_ws, size_t ws_size,
                              hipStream_t stream) {
    const float* X  = (const float*)d_in[0];
    const float* Y  = (const float*)d_in[1];
    const float* Wq = (const float*)d_in[2];
    const float* Wk = (const float*)d_in[3];
    const float* Wv = (const float*)d_in[4];
    float* out = (float*)d_out;

    const long NTOK = 16384, D = 1024;
    // fp16 workspace. Aliases (all stream-ordered safe):
    //   Kh = Yh   (Yh dead after Q-projection)
    //   Pg,invSum over Xh (Xh dead after V-projection; qk_kernel runs after)
    char* p = (char*)d_ws;
    _Float16* Xh  = (_Float16*)p; p += NTOK * D * 2;   // 32 MB
    _Float16* Yh  = (_Float16*)p; p += NTOK * D * 2;   // 32 MB (reused as Kh)
    _Float16* Wqh = (_Float16*)p; p += D * D * 2;      //  2 MB (pre-scaled by 1/32)
    _Float16* Wkh = (_Float16*)p; p += D * D * 2;
    _Float16* Wvh = (_Float16*)p; p += D * D * 2;
    _Float16* Qh  = (_Float16*)p; p += NTOK * D * 2;   // 32 MB
    _Float16* Vt  = (_Float16*)p; p += NTOK * D * 2;   // 32 MB  [D][NTOK]
    _Float16* Kh  = Yh;
    _Float16* Pg  = Xh;                                // 256*64*576*2 = 18.9 MB
    float* invSum = (float*)(Xh + 256l * 64 * 576);    // 64 KB, still inside Xh

    const int nT = (int)(NTOK * D);
    const int nW = (int)(D * D);
    cvt_kernel<<<nT / 2048, 256, 0, stream>>>(X, Xh, nT, 1.f);
    cvt_kernel<<<nT / 2048, 256, 0, stream>>>(Y, Yh, nT, 1.f);
    cvt_kernel<<<nW / 2048, 256, 0, stream>>>(Wq, Wqh, nW, 0.03125f);  // fold 1/sqrt(1024)
    cvt_kernel<<<nW / 2048, 256, 0, stream>>>(Wk, Wkh, nW, 1.f);
    cvt_kernel<<<nW / 2048, 256, 0, stream>>>(Wv, Wvh, nW, 1.f);

    // Q = Y Wq^T (scaled), K = X Wk^T, Vt = Wv X^T
    gemm_bt<<<dim3(1024 / 128, 16384 / 128), 256, 0, stream>>>(Yh, Wqh, Qh, 16384, 1024, 1024);
    gemm_bt<<<dim3(1024 / 128, 16384 / 128), 256, 0, stream>>>(Xh, Wkh, Kh, 16384, 1024, 1024);
    gemm_bt<<<dim3(16384 / 128, 1024 / 128), 256, 0, stream>>>(Wvh, Xh, Vt, 1024, 16384, 1024);

    qk_kernel<<<dim3(256), 512, 0, stream>>>(Qh, Kh, Pg, invSum);
    pv_kernel<<<dim3(4 * 256), 512, 0, stream>>>(Pg, invSum, Vt, out);
}

// Round 4
// 410.313 us; speedup vs baseline: 1.1889x; 1.0036x over previous
//
#include <hip/hip_runtime.h>
#include <hip/hip_bf16.h>
#include <stdint.h>

// ---------- types ----------
typedef _Float16 half8 __attribute__((ext_vector_type(8)));
typedef float floatx4 __attribute__((ext_vector_type(4)));

#define MFMA16(a, b, c) __builtin_amdgcn_mfma_f32_16x16x32_f16(a, b, c, 0, 0, 0)

// async global->LDS, 16B per lane, dest = wave-uniform base + lane*16
__device__ __forceinline__ void async_load16(const void* g, void* l) {
    __builtin_amdgcn_global_load_lds((__attribute__((address_space(1))) void*)(g),
                                     (__attribute__((address_space(3))) void*)(l),
                                     16, 0, 0);
}

// LDS XOR swizzle for [row][32]-fp16 tiles (4 x 16B granules per 64B row):
//   stored slot p of row r holds global granule p ^ ((r>>1)&3)
//   reader at quad q reads slot q ^ ((r>>1)&3)  -> global granule q
// 16 row-lanes then span all 32 banks at 2-way (free) instead of 8-way.
// Staging lanes have r = base + (lane>>2), p = lane&3, so the pre-swizzled global
// granule is (lane&3) ^ ((lane>>3)&3) -- LDS dest stays linear (rule #21).
// (+128-row second load: (row+128)>>1 & 3 == (row>>1)&3, same formula holds.)

// ---------- fp32 -> fp16 conversion (with optional scale) ----------
__global__ __launch_bounds__(256) void cvt_kernel(const float* __restrict__ in,
                                                  _Float16* __restrict__ out,
                                                  int n, float scale) {
    int i = (blockIdx.x * 256 + threadIdx.x) * 8;
    if (i >= n) return;
    float4 v0 = *(const float4*)(in + i);
    float4 v1 = *(const float4*)(in + i + 4);
    half8 h;
    h[0] = (_Float16)(v0.x * scale);
    h[1] = (_Float16)(v0.y * scale);
    h[2] = (_Float16)(v0.z * scale);
    h[3] = (_Float16)(v0.w * scale);
    h[4] = (_Float16)(v1.x * scale);
    h[5] = (_Float16)(v1.y * scale);
    h[6] = (_Float16)(v1.z * scale);
    h[7] = (_Float16)(v1.w * scale);
    *(half8*)(out + i) = h;
}

// ---------- C[m][n] = sum_k A[m][k] * B[n][k] ----------
// 256x256 tile, BK=32, 8 waves (2M x 4N, per-wave 128x64); double-buffered LDS
// (2 x 32 KB), ONE barrier per k-chunk. 256^2 doubles arithmetic intensity per
// staged byte vs 128^2: per k-step 32 KB L2 -> 256 MFMA (1242 cyc CU matrix
// time vs 585 cyc L2 service), flipping the step floor from L2-queue to MFMA.
// XCD-chunked remap + both-sides XOR swizzle retained (proven: fetch=ideal,
// conflicts=0). 1 block/CU (LDS 64 KB, ~200 VGPR), single grid round.
__global__ __launch_bounds__(512, 2) void gemm_bt(const _Float16* __restrict__ A,
                                                  const _Float16* __restrict__ B,
                                                  _Float16* __restrict__ C,
                                                  int M, int N, int K) {
    __shared__ _Float16 sA[2][256 * 32];   // 2 x 16 KB
    __shared__ _Float16 sB[2][256 * 32];
    const int tid  = threadIdx.x;
    const int lane = tid & 63;
    const int w    = tid >> 6;
    const int quad = lane >> 4;
    const int m16  = lane & 15;
    const int wm   = (w >> 2) * 128;    // 2 wave-rows
    const int wn   = (w & 3) * 64;      // 4 wave-cols

    // bijective XCD-chunk remap (total % 8 == 0). Fast axis inside a chunk is
    // the SMALL grid dim (full small-dim strips per XCD -> max panel reuse).
    const int gx = gridDim.x, gy = gridDim.y;
    const int total = gx * gy;
    const int id = blockIdx.y * gx + blockIdx.x;
    const int logical = (id & 7) * (total >> 3) + (id >> 3);
    int bx, by;
    if (gx <= gy) { bx = logical % gx; by = logical / gx; }
    else          { by = logical % gy; bx = logical / gy; }
    const long row0 = (long)by * 256;
    const long col0 = (long)bx * 256;

    floatx4 acc[8][4] = {};

    const int swz = ((tid & 3) ^ ((tid >> 3) & 3)) * 8;   // pre-swizzled granule
    const _Float16* ga0 = A + (row0 + (tid >> 2)) * (long)K + swz;   // rows 0..127
    const _Float16* ga1 = ga0 + 128l * K;                            // rows 128..255
    const _Float16* gb0 = B + (col0 + (tid >> 2)) * (long)K + swz;
    const _Float16* gb1 = gb0 + 128l * K;
    const int wchunk = w * 1024;        // wave-uniform byte base (16 rows x 64 B)

    auto stage = [&](int bi, int kc) {
        char* lA = (char*)sA[bi] + wchunk;
        char* lB = (char*)sB[bi] + wchunk;
        async_load16(ga0 + kc, lA);
        async_load16(ga1 + kc, lA + 8192);
        async_load16(gb0 + kc, lB);
        async_load16(gb1 + kc, lB + 8192);
    };

    const int rswz = (m16 >> 1) & 3;    // == (row>>1)&3 for row = base16 + m16

    stage(0, 0);
    for (int kc = 0; kc < K; kc += 32) {
        const int bi = (kc >> 5) & 1;
        __syncthreads();                    // drains prefetch of THIS chunk
        if (kc + 32 < K) stage(bi ^ 1, kc + 32);
        half8 af[8], bf[4];
#pragma unroll
        for (int mt = 0; mt < 8; mt++)
            af[mt] = *(const half8*)(sA[bi] + (wm + mt * 16 + m16) * 32 + (quad ^ rswz) * 8);
#pragma unroll
        for (int nt = 0; nt < 4; nt++)
            bf[nt] = *(const half8*)(sB[bi] + (wn + nt * 16 + m16) * 32 + (quad ^ rswz) * 8);
#pragma unroll
        for (int mt = 0; mt < 8; mt++)
#pragma unroll
            for (int nt = 0; nt < 4; nt++)
                acc[mt][nt] = MFMA16(af[mt], bf[nt], acc[mt][nt]);
    }

#pragma unroll
    for (int mt = 0; mt < 8; mt++)
#pragma unroll
        for (int nt = 0; nt < 4; nt++)
#pragma unroll
            for (int reg = 0; reg < 4; reg++) {
                long r = row0 + wm + mt * 16 + quad * 4 + reg;
                long c = col0 + wn + nt * 16 + m16;
                C[r * N + c] = (_Float16)acc[mt][nt][reg];
            }
}

// ---------- attention kernel A: banded S = Q K^T -> softmax -> P (fp16) ----------
// block = 64 q-rows, 512 threads / 8 waves. Whole K band chunk staged in LDS.
// XCD-chunked qblk remap (qblk/32 == XCD) pairs with pv's remap for L2 locality.
// LDS tiles use the XOR swizzle above (conflict-free ds_read_b128).
__global__ __launch_bounds__(512) void qk_kernel(const _Float16* __restrict__ Qh,
                                                 const _Float16* __restrict__ Kh,
                                                 _Float16* __restrict__ Pg,
                                                 float* __restrict__ invSum) {
    const int S = 4096, D = 1024;
    __shared__ _Float16 sK[2][576 * 32];   // 2 x 36 KB
    __shared__ _Float16 sQ[2][64 * 32];    // 2 x 4 KB
    __shared__ float sMax[64][8];
    __shared__ float sSum[64][8];

    const int tid  = threadIdx.x;
    const int lane = tid & 63;
    const int w    = tid >> 6;
    const int quad = lane >> 4;
    const int c16  = lane & 15;
    // bijective XCD-chunk remap (256 % 8 == 0)
    const int qblk = (blockIdx.x & 7) * 32 + (blockIdx.x >> 3);
    const int b    = qblk >> 6;
    const int q0   = (qblk & 63) << 6;

    int kstart = q0 - 256; if (kstart < 0) kstart = 0;   // multiple of 64
    int kend   = q0 + 320; if (kend > S) kend = S;       // multiple of 64
    const int L = kend - kstart;        // 320..576, multiple of 64
    const int ntiles = L >> 4;          // <= 36

    const int lrow = lane >> 2;                          // 0..15
    const int swz  = ((lane & 3) ^ ((lane >> 3) & 3)) * 8;  // pre-swizzled granule
    const _Float16* Kbase = Kh + ((long)(b * S + kstart) + lrow) * D + swz;
    const _Float16* Qbase = Qh + ((long)(b * S + q0) + w * 16 + lrow) * D + swz;

    auto stage = [&](int bi, int kc) {
#pragma unroll
        for (int j = 0; j < 5; j++) {
            int g = j * 8 + w;                       // 16-row group, wave-uniform
            if (g < ntiles)
                async_load16(Kbase + (long)g * 16 * D + kc, (char*)sK[bi] + g * 1024);
        }
        if (w < 4)
            async_load16(Qbase + kc, (char*)sQ[bi] + w * 1024);
    };

    const int rswz = ((c16 >> 1) & 3);   // == (row>>1)&3 for row = 16*base + c16

    floatx4 acc[4][5] = {};
    stage(0, 0);
    for (int kc = 0; kc < 1024; kc += 32) {
        const int bi = (kc >> 5) & 1;
        __syncthreads();
        if (kc + 32 < 1024) stage(bi ^ 1, kc + 32);
        half8 aQ[4];
#pragma unroll
        for (int mt = 0; mt < 4; mt++)
            aQ[mt] = *(const half8*)(sQ[bi] + (mt * 16 + c16) * 32 + (quad ^ rswz) * 8);
#pragma unroll
        for (int i = 0; i < 5; i++) {
            int t = w + i * 8;
            if (t < ntiles) {                        // wave-uniform
                half8 bK = *(const half8*)(sK[bi] + (t * 16 + c16) * 32 + (quad ^ rswz) * 8);
#pragma unroll
                for (int mt = 0; mt < 4; mt++)
                    acc[mt][i] = MFMA16(aQ[mt], bK, acc[mt][i]);
            }
        }
    }

    // band mask
#pragma unroll
    for (int i = 0; i < 5; i++) {
        int t = w + i * 8;
        if (t < ntiles) {
            int j = kstart + t * 16 + c16;
#pragma unroll
            for (int mt = 0; mt < 4; mt++)
#pragma unroll
                for (int r = 0; r < 4; r++) {
                    int qi = q0 + mt * 16 + quad * 4 + r;
                    int dd = qi - j; dd = dd < 0 ? -dd : dd;
                    if (dd > 256) acc[mt][i][r] = -1e30f;
                }
        }
    }
    // partial row max (this wave's band-eighth), reduce over the 16-lane col group
#pragma unroll
    for (int mt = 0; mt < 4; mt++)
#pragma unroll
        for (int r = 0; r < 4; r++) {
            float m = -1e30f;
#pragma unroll
            for (int i = 0; i < 5; i++)
                if (w + i * 8 < ntiles) m = fmaxf(m, acc[mt][i][r]);
#pragma unroll
            for (int off = 1; off < 16; off <<= 1) m = fmaxf(m, __shfl_xor(m, off, 64));
            if (c16 == 0) sMax[mt * 16 + quad * 4 + r][w] = m;
        }
    __syncthreads();
    if (tid < 64) {
        float fm = sMax[tid][0];
#pragma unroll
        for (int j = 1; j < 8; j++) fm = fmaxf(fm, sMax[tid][j]);
        sMax[tid][0] = fm;
    }
    __syncthreads();
    // exp, write P, partial sums
#pragma unroll
    for (int mt = 0; mt < 4; mt++)
#pragma unroll
        for (int r = 0; r < 4; r++) {
            int row = mt * 16 + quad * 4 + r;
            float fm = sMax[row][0];
            float s = 0.f;
#pragma unroll
            for (int i = 0; i < 5; i++) {
                int t = w + i * 8;
                if (t < ntiles) {
                    float e = __expf(acc[mt][i][r] - fm);   // masked -> 0
                    s += e;
                    Pg[(long)qblk * 36864 + row * 576 + t * 16 + c16] = (_Float16)e;
                }
            }
#pragma unroll
            for (int off = 1; off < 16; off <<= 1) s += __shfl_xor(s, off, 64);
            if (c16 == 0) sSum[row][w] = s;
        }
    __syncthreads();
    if (tid < 64) {
        float t = 0.f;
#pragma unroll
        for (int j = 0; j < 8; j++) t += sSum[tid][j];
        invSum[qblk * 64 + tid] = 1.f / t;
    }
}

// ---------- attention kernel B: O = P V (banded), from Vt [d][tok] ----------
// LDS-staged 2-phase structure + XCD-chunked remap (Pg/Vt L2-resident) +
// XOR-swizzled LDS (conflict-free ds_read_b128).
__global__ __launch_bounds__(512) void pv_kernel(const _Float16* __restrict__ Pg,
                                                 const float* __restrict__ invSum,
                                                 const _Float16* __restrict__ Vt,
                                                 float* __restrict__ out) {
    const int S = 4096, D = 1024, TOK = 16384;
    __shared__ _Float16 sA[2][64 * 32];    // 2 x 4 KB
    __shared__ _Float16 sB[2][256 * 32];   // 2 x 16 KB

    const int tid  = threadIdx.x;
    const int lane = tid & 63;
    const int w    = tid >> 6;
    const int quad = lane >> 4;
    const int c16  = lane & 15;

    // bijective XCD-chunk remap (1024 % 8 == 0); n-block inner, qblk outer
    const int logical = (blockIdx.x & 7) * 128 + (blockIdx.x >> 3);
    const int qblk = logical >> 2;      // qblk/32 == XCD id, matches qk_kernel
    const int n0   = (logical & 3) << 8;
    const int b    = qblk >> 6;
    const int q0   = (qblk & 63) << 6;

    int kstart = q0 - 256; if (kstart < 0) kstart = 0;
    int kend   = q0 + 320; if (kend > S) kend = S;
    const int nsteps = (kend - kstart) >> 5;   // 10..18, even

    const int lrow = lane >> 2;
    const int swz  = ((lane & 3) ^ ((lane >> 3) & 3)) * 8;  // pre-swizzled granule
    const _Float16* Abase = Pg + (long)qblk * 36864 + (w * 16 + lrow) * 576 + swz;
    const _Float16* Bbase = Vt + (long)(n0 + lrow) * TOK + b * S + kstart + swz;

    auto stage = [&](int bi, int kc) {
        if (w < 4)
            async_load16(Abase + kc, (char*)sA[bi] + w * 1024);
#pragma unroll
        for (int j = 0; j < 2; j++) {
            int g = j * 8 + w;
            async_load16(Bbase + (long)g * 16 * TOK + kc, (char*)sB[bi] + g * 1024);
        }
    };

    const int wm = (w >> 2) * 32;
    const int wn = (w & 3) * 64;
    const int rswz = ((c16 >> 1) & 3);   // == (row>>1)&3 for row = 16*base + c16
    floatx4 acc[2][4] = {};

    stage(0, 0);
    for (int s = 0; s < nsteps; s++) {
        const int bi = s & 1;
        __syncthreads();
        if (s + 1 < nsteps) stage(bi ^ 1, (s + 1) * 32);
        half8 aA[2], bB[4];
#pragma unroll
        for (int mt = 0; mt < 2; mt++)
            aA[mt] = *(const half8*)(sA[bi] + (wm + mt * 16 + c16) * 32 + (quad ^ rswz) * 8);
#pragma unroll
        for (int nt = 0; nt < 4; nt++)
            bB[nt] = *(const half8*)(sB[bi] + (wn + nt * 16 + c16) * 32 + (quad ^ rswz) * 8);
#pragma unroll
        for (int mt = 0; mt < 2; mt++)
#pragma unroll
            for (int nt = 0; nt < 4; nt++)
                acc[mt][nt] = MFMA16(aA[mt], bB[nt], acc[mt][nt]);
    }

    const float* isB = invSum + qblk * 64;
#pragma unroll
    for (int mt = 0; mt < 2; mt++)
#pragma unroll
        for (int nt = 0; nt < 4; nt++)
#pragma unroll
            for (int reg = 0; reg < 4; reg++) {
                int row = wm + mt * 16 + quad * 4 + reg;
                int col = n0 + wn + nt * 16 + c16;
                out[(long)(b * S + q0 + row) * D + col] = acc[mt][nt][reg] * isB[row];
            }
}

extern "C" void kernel_launch(void* const* d_in, const int* in_sizes, int n_in,
                              void* d_out, int out_size, void* d_ws, size_t ws_size,
                              hipStream_t stream) {
    const float* X  = (const float*)d_in[0];
    const float* Y  = (const float*)d_in[1];
    const float* Wq = (const float*)d_in[2];
    const float* Wk = (const float*)d_in[3];
    const float* Wv = (const float*)d_in[4];
    float* out = (float*)d_out;

    const long NTOK = 16384, D = 1024;
    // fp16 workspace. Aliases (all stream-ordered safe):
    //   Kh = Yh   (Yh dead after Q-projection)
    //   Pg,invSum over Xh (Xh dead after V-projection; qk_kernel runs after)
    char* p = (char*)d_ws;
    _Float16* Xh  = (_Float16*)p; p += NTOK * D * 2;   // 32 MB
    _Float16* Yh  = (_Float16*)p; p += NTOK * D * 2;   // 32 MB (reused as Kh)
    _Float16* Wqh = (_Float16*)p; p += D * D * 2;      //  2 MB (pre-scaled by 1/32)
    _Float16* Wkh = (_Float16*)p; p += D * D * 2;
    _Float16* Wvh = (_Float16*)p; p += D * D * 2;
    _Float16* Qh  = (_Float16*)p; p += NTOK * D * 2;   // 32 MB
    _Float16* Vt  = (_Float16*)p; p += NTOK * D * 2;   // 32 MB  [D][NTOK]
    _Float16* Kh  = Yh;
    _Float16* Pg  = Xh;                                // 256*64*576*2 = 18.9 MB
    float* invSum = (float*)(Xh + 256l * 64 * 576);    // 64 KB, still inside Xh

    const int nT = (int)(NTOK * D);
    const int nW = (int)(D * D);
    cvt_kernel<<<nT / 2048, 256, 0, stream>>>(X, Xh, nT, 1.f);
    cvt_kernel<<<nT / 2048, 256, 0, stream>>>(Y, Yh, nT, 1.f);
    cvt_kernel<<<nW / 2048, 256, 0, stream>>>(Wq, Wqh, nW, 0.03125f);  // fold 1/sqrt(1024)
    cvt_kernel<<<nW / 2048, 256, 0, stream>>>(Wk, Wkh, nW, 1.f);
    cvt_kernel<<<nW / 2048, 256, 0, stream>>>(Wv, Wvh, nW, 1.f);

    // Q = Y Wq^T (scaled), K = X Wk^T, Vt = Wv X^T  (256^2 tiles)
    gemm_bt<<<dim3(1024 / 256, 16384 / 256), 512, 0, stream>>>(Yh, Wqh, Qh, 16384, 1024, 1024);
    gemm_bt<<<dim3(1024 / 256, 16384 / 256), 512, 0, stream>>>(Xh, Wkh, Kh, 16384, 1024, 1024);
    gemm_bt<<<dim3(16384 / 256, 1024 / 256), 512, 0, stream>>>(Wvh, Xh, Vt, 1024, 16384, 1024);

    qk_kernel<<<dim3(256), 512, 0, stream>>>(Qh, Kh, Pg, invSum);
    pv_kernel<<<dim3(4 * 256), 512, 0, stream>>>(Pg, invSum, Vt, out);
}

// Round 5
// 377.329 us; speedup vs baseline: 1.2928x; 1.0874x over previous
//
#include <hip/hip_runtime.h>
#include <hip/hip_bf16.h>
#include <stdint.h>

// ---------- types ----------
typedef _Float16 half8 __attribute__((ext_vector_type(8)));
typedef float floatx4 __attribute__((ext_vector_type(4)));

#define MFMA16(a, b, c) __builtin_amdgcn_mfma_f32_16x16x32_f16(a, b, c, 0, 0, 0)

// async global->LDS, 16B per lane, dest = wave-uniform base + lane*16
__device__ __forceinline__ void async_load16(const void* g, void* l) {
    __builtin_amdgcn_global_load_lds((__attribute__((address_space(1))) void*)(g),
                                     (__attribute__((address_space(3))) void*)(l),
                                     16, 0, 0);
}

#define RAW_BARRIER()  asm volatile("s_barrier" ::: "memory")
#define WAIT_VMCNT(n)  asm volatile("s_waitcnt vmcnt(" #n ")" ::: "memory")
#define WAIT_LGKM0()   asm volatile("s_waitcnt lgkmcnt(0)" ::: "memory")

// LDS XOR swizzle for [row][32]-fp16 panels (4 x 16B granules per 64B row):
//   stored slot p of row r holds global granule p ^ ((r>>1)&3)
//   reader at quad q reads slot q ^ ((r>>1)&3)  -> global granule q
// Staging lanes have r = base + (tid>>2), p = tid&3, so the pre-swizzled global
// granule is (tid&3) ^ ((tid>>3)&3) -- LDS dest stays linear (rule #21).

// ---------- fp32 -> fp16 conversion (with optional scale) ----------
__global__ __launch_bounds__(256) void cvt_kernel(const float* __restrict__ in,
                                                  _Float16* __restrict__ out,
                                                  int n, float scale) {
    int i = (blockIdx.x * 256 + threadIdx.x) * 8;
    if (i >= n) return;
    float4 v0 = *(const float4*)(in + i);
    float4 v1 = *(const float4*)(in + i + 4);
    half8 h;
    h[0] = (_Float16)(v0.x * scale);
    h[1] = (_Float16)(v0.y * scale);
    h[2] = (_Float16)(v0.z * scale);
    h[3] = (_Float16)(v0.w * scale);
    h[4] = (_Float16)(v1.x * scale);
    h[5] = (_Float16)(v1.y * scale);
    h[6] = (_Float16)(v1.z * scale);
    h[7] = (_Float16)(v1.w * scale);
    *(half8*)(out + i) = h;
}

// ---------- C[m][n] = sum_k A[m][k] * B[n][k] ----------
// 256x256 tile, BK=64 (2 x 32-col ksub panels), 8 waves, 8-phase schedule with
// COUNTED vmcnt (T3+T4): per BK-tile 4 quadrant-phases, each
// {ds_read quad || stage 1 half-tile -> s_barrier -> lgkmcnt(0) ->
//  setprio(1) 16 MFMA setprio(0) -> s_barrier}; vmcnt(4) once per tile (p3),
// NEVER 0 in steady state -> 2 half-tiles stay in flight across barriers.
// This breaks the measured 2-phase 607-TF stall (m233/m248: 2ph=607-655,
// 8ph=848+ at the same K=1024 shape).
// Wave frag mapping is aligned to 128-row staging halves so quadrant mh/nh
// touches exactly one A/B half: A0 read only @p0,p1 (freed for (U+2).A0 stage
// @p2); B0 @p0,p2 (stage @p3); B1 @p1,p3; A1 @p2,p3 ((U+1) staged @p0,p1 of
// tile U). vmcnt(4) @p3 => tile U+1 fully resident, tile U+2 halves in flight.
// Raw asm barriers (no compiler vmcnt(0) drain); XCD remap + XOR swizzle kept.
__global__ __launch_bounds__(512, 2) void gemm_bt(const _Float16* __restrict__ A,
                                                  const _Float16* __restrict__ B,
                                                  _Float16* __restrict__ C,
                                                  int M, int N, int K) {
    __shared__ _Float16 sA[2][2][256 * 32];   // [buf][ksub][256 x 32] = 64 KB
    __shared__ _Float16 sB[2][2][256 * 32];   // 64 KB
    const int tid  = threadIdx.x;
    const int lane = tid & 63;
    const int w    = tid >> 6;
    const int quad = lane >> 4;
    const int m16  = lane & 15;
    const int mq   = (w >> 2) * 64;     // wave m quarter base within a 128-half
    const int nq   = (w & 3) * 32;      // wave n strip base within a 128-half

    // bijective XCD-chunk remap (total % 8 == 0), small grid dim fast.
    const int gx = gridDim.x, gy = gridDim.y;
    const int total = gx * gy;
    const int id = blockIdx.y * gx + blockIdx.x;
    const int logical = (id & 7) * (total >> 3) + (id >> 3);
    int bx, by;
    if (gx <= gy) { bx = logical % gx; by = logical / gx; }
    else          { by = logical % gy; bx = logical / gy; }
    const long row0 = (long)by * 256;
    const long col0 = (long)bx * 256;

    floatx4 acc[8][4] = {};

    const int swz = ((tid & 3) ^ ((tid >> 3) & 3)) * 8;   // pre-swizzled granule
    const _Float16* ga = A + (row0 + (tid >> 2)) * (long)K + swz;
    const _Float16* gb = B + (col0 + (tid >> 2)) * (long)K + swz;
    const int wchunk = w * 1024;        // wave-uniform byte base in a 128x32 panel

    auto stageA = [&](int tile, int half) {
        const int s = tile & 1;
        char* l0 = (char*)sA[s][0] + half * 8192 + wchunk;
        char* l1 = (char*)sA[s][1] + half * 8192 + wchunk;
        const _Float16* g = ga + (long)tile * 64 + (long)half * 128 * K;
        async_load16(g, l0);
        async_load16(g + 32, l1);
    };
    auto stageB = [&](int tile, int half) {
        const int s = tile & 1;
        char* l0 = (char*)sB[s][0] + half * 8192 + wchunk;
        char* l1 = (char*)sB[s][1] + half * 8192 + wchunk;
        const _Float16* g = gb + (long)tile * 64 + (long)half * 128 * K;
        async_load16(g, l0);
        async_load16(g + 32, l1);
    };

    const int rswz = (m16 >> 1) & 3;    // == (row>>1)&3 for row = base16 + m16
    const int NTt  = K >> 6;            // BK=64 tiles (16 for K=1024)

    // prologue: tile0 all 4 half-tiles + tile1 {A0,B0}  (12 loads/wave)
    stageA(0, 0); stageA(0, 1); stageB(0, 0); stageB(0, 1);
    stageA(1, 0); stageB(1, 0);
    WAIT_VMCNT(4);                      // tile0 resident; tile1 halves in flight
    RAW_BARRIER();

    for (int U = 0; U < NTt; ++U) {
        const int s = U & 1;
        const int T1 = U + 1, T2 = U + 2;
        half8 af[4][2], bf[2][2];
#pragma unroll
        for (int p = 0; p < 4; ++p) {
            const int mh = p >> 1, nh = p & 1;   // quadrant = (m-half, n-half)
            if ((p & 1) == 0) {                  // A frags reused across nh
#pragma unroll
                for (int mt = 0; mt < 4; mt++)
#pragma unroll
                    for (int j = 0; j < 2; j++)
                        af[mt][j] = *(const half8*)(sA[s][j] +
                            (mh * 128 + mq + mt * 16 + m16) * 32 + (quad ^ rswz) * 8);
            }
#pragma unroll
            for (int nt = 0; nt < 2; nt++)
#pragma unroll
                for (int j = 0; j < 2; j++)
                    bf[nt][j] = *(const half8*)(sB[s][j] +
                        (nh * 128 + nq + nt * 16 + m16) * 32 + (quad ^ rswz) * 8);
            // staging pattern (slot freed by preceding phase's last reader)
            if (p == 0 && T1 < NTt) stageB(T1, 1);
            if (p == 1 && T1 < NTt) stageA(T1, 1);
            if (p == 2 && T2 < NTt) stageA(T2, 0);
            if (p == 3 && T2 < NTt) stageB(T2, 0);
            if (p == 3) {
                if (T2 < NTt) { WAIT_VMCNT(4); }   // tile U+1 resident, U+2 in flight
                else          { WAIT_VMCNT(0); }   // tail drain
            }
            RAW_BARRIER();
            WAIT_LGKM0();
            __builtin_amdgcn_sched_barrier(0);
            __builtin_amdgcn_s_setprio(1);
#pragma unroll
            for (int mt = 0; mt < 4; mt++)
#pragma unroll
                for (int nt = 0; nt < 2; nt++) {
                    acc[mh * 4 + mt][nh * 2 + nt] =
                        MFMA16(af[mt][0], bf[nt][0], acc[mh * 4 + mt][nh * 2 + nt]);
                    acc[mh * 4 + mt][nh * 2 + nt] =
                        MFMA16(af[mt][1], bf[nt][1], acc[mh * 4 + mt][nh * 2 + nt]);
                }
            __builtin_amdgcn_s_setprio(0);
            RAW_BARRIER();
        }
    }

    // epilogue: frag MT>=4 lives in rows 128+, NT2>=2 in cols 128+
#pragma unroll
    for (int mt = 0; mt < 8; mt++)
#pragma unroll
        for (int nt = 0; nt < 4; nt++)
#pragma unroll
            for (int reg = 0; reg < 4; reg++) {
                long r = row0 + (mt >> 2) * 128 + mq + (mt & 3) * 16 + quad * 4 + reg;
                long c = col0 + (nt >> 1) * 128 + nq + (nt & 1) * 16 + m16;
                C[r * N + c] = (_Float16)acc[mt][nt][reg];
            }
}

// ---------- attention kernel A: banded S = Q K^T -> softmax -> P (fp16) ----------
// block = 64 q-rows, 512 threads / 8 waves. Whole K band chunk staged in LDS.
// XCD-chunked qblk remap (qblk/32 == XCD) pairs with pv's remap for L2 locality.
// LDS tiles use the XOR swizzle above (conflict-free ds_read_b128).
__global__ __launch_bounds__(512) void qk_kernel(const _Float16* __restrict__ Qh,
                                                 const _Float16* __restrict__ Kh,
                                                 _Float16* __restrict__ Pg,
                                                 float* __restrict__ invSum) {
    const int S = 4096, D = 1024;
    __shared__ _Float16 sK[2][576 * 32];   // 2 x 36 KB
    __shared__ _Float16 sQ[2][64 * 32];    // 2 x 4 KB
    __shared__ float sMax[64][8];
    __shared__ float sSum[64][8];

    const int tid  = threadIdx.x;
    const int lane = tid & 63;
    const int w    = tid >> 6;
    const int quad = lane >> 4;
    const int c16  = lane & 15;
    // bijective XCD-chunk remap (256 % 8 == 0)
    const int qblk = (blockIdx.x & 7) * 32 + (blockIdx.x >> 3);
    const int b    = qblk >> 6;
    const int q0   = (qblk & 63) << 6;

    int kstart = q0 - 256; if (kstart < 0) kstart = 0;   // multiple of 64
    int kend   = q0 + 320; if (kend > S) kend = S;       // multiple of 64
    const int L = kend - kstart;        // 320..576, multiple of 64
    const int ntiles = L >> 4;          // <= 36

    const int lrow = lane >> 2;                          // 0..15
    const int swz  = ((lane & 3) ^ ((lane >> 3) & 3)) * 8;  // pre-swizzled granule
    const _Float16* Kbase = Kh + ((long)(b * S + kstart) + lrow) * D + swz;
    const _Float16* Qbase = Qh + ((long)(b * S + q0) + w * 16 + lrow) * D + swz;

    auto stage = [&](int bi, int kc) {
#pragma unroll
        for (int j = 0; j < 5; j++) {
            int g = j * 8 + w;                       // 16-row group, wave-uniform
            if (g < ntiles)
                async_load16(Kbase + (long)g * 16 * D + kc, (char*)sK[bi] + g * 1024);
        }
        if (w < 4)
            async_load16(Qbase + kc, (char*)sQ[bi] + w * 1024);
    };

    const int rswz = ((c16 >> 1) & 3);   // == (row>>1)&3 for row = 16*base + c16

    floatx4 acc[4][5] = {};
    stage(0, 0);
    for (int kc = 0; kc < 1024; kc += 32) {
        const int bi = (kc >> 5) & 1;
        __syncthreads();
        if (kc + 32 < 1024) stage(bi ^ 1, kc + 32);
        half8 aQ[4];
#pragma unroll
        for (int mt = 0; mt < 4; mt++)
            aQ[mt] = *(const half8*)(sQ[bi] + (mt * 16 + c16) * 32 + (quad ^ rswz) * 8);
#pragma unroll
        for (int i = 0; i < 5; i++) {
            int t = w + i * 8;
            if (t < ntiles) {                        // wave-uniform
                half8 bK = *(const half8*)(sK[bi] + (t * 16 + c16) * 32 + (quad ^ rswz) * 8);
#pragma unroll
                for (int mt = 0; mt < 4; mt++)
                    acc[mt][i] = MFMA16(aQ[mt], bK, acc[mt][i]);
            }
        }
    }

    // band mask
#pragma unroll
    for (int i = 0; i < 5; i++) {
        int t = w + i * 8;
        if (t < ntiles) {
            int j = kstart + t * 16 + c16;
#pragma unroll
            for (int mt = 0; mt < 4; mt++)
#pragma unroll
                for (int r = 0; r < 4; r++) {
                    int qi = q0 + mt * 16 + quad * 4 + r;
                    int dd = qi - j; dd = dd < 0 ? -dd : dd;
                    if (dd > 256) acc[mt][i][r] = -1e30f;
                }
        }
    }
    // partial row max (this wave's band-eighth), reduce over the 16-lane col group
#pragma unroll
    for (int mt = 0; mt < 4; mt++)
#pragma unroll
        for (int r = 0; r < 4; r++) {
            float m = -1e30f;
#pragma unroll
            for (int i = 0; i < 5; i++)
                if (w + i * 8 < ntiles) m = fmaxf(m, acc[mt][i][r]);
#pragma unroll
            for (int off = 1; off < 16; off <<= 1) m = fmaxf(m, __shfl_xor(m, off, 64));
            if (c16 == 0) sMax[mt * 16 + quad * 4 + r][w] = m;
        }
    __syncthreads();
    if (tid < 64) {
        float fm = sMax[tid][0];
#pragma unroll
        for (int j = 1; j < 8; j++) fm = fmaxf(fm, sMax[tid][j]);
        sMax[tid][0] = fm;
    }
    __syncthreads();
    // exp, write P, partial sums
#pragma unroll
    for (int mt = 0; mt < 4; mt++)
#pragma unroll
        for (int r = 0; r < 4; r++) {
            int row = mt * 16 + quad * 4 + r;
            float fm = sMax[row][0];
            float s = 0.f;
#pragma unroll
            for (int i = 0; i < 5; i++) {
                int t = w + i * 8;
                if (t < ntiles) {
                    float e = __expf(acc[mt][i][r] - fm);   // masked -> 0
                    s += e;
                    Pg[(long)qblk * 36864 + row * 576 + t * 16 + c16] = (_Float16)e;
                }
            }
#pragma unroll
            for (int off = 1; off < 16; off <<= 1) s += __shfl_xor(s, off, 64);
            if (c16 == 0) sSum[row][w] = s;
        }
    __syncthreads();
    if (tid < 64) {
        float t = 0.f;
#pragma unroll
        for (int j = 0; j < 8; j++) t += sSum[tid][j];
        invSum[qblk * 64 + tid] = 1.f / t;
    }
}

// ---------- attention kernel B: O = P V (banded), from Vt [d][tok] ----------
// LDS-staged 2-phase structure + XCD-chunked remap (Pg/Vt L2-resident) +
// XOR-swizzled LDS (conflict-free ds_read_b128).
__global__ __launch_bounds__(512) void pv_kernel(const _Float16* __restrict__ Pg,
                                                 const float* __restrict__ invSum,
                                                 const _Float16* __restrict__ Vt,
                                                 float* __restrict__ out) {
    const int S = 4096, D = 1024, TOK = 16384;
    __shared__ _Float16 sA[2][64 * 32];    // 2 x 4 KB
    __shared__ _Float16 sB[2][256 * 32];   // 2 x 16 KB

    const int tid  = threadIdx.x;
    const int lane = tid & 63;
    const int w    = tid >> 6;
    const int quad = lane >> 4;
    const int c16  = lane & 15;

    // bijective XCD-chunk remap (1024 % 8 == 0); n-block inner, qblk outer
    const int logical = (blockIdx.x & 7) * 128 + (blockIdx.x >> 3);
    const int qblk = logical >> 2;      // qblk/32 == XCD id, matches qk_kernel
    const int n0   = (logical & 3) << 8;
    const int b    = qblk >> 6;
    const int q0   = (qblk & 63) << 6;

    int kstart = q0 - 256; if (kstart < 0) kstart = 0;
    int kend   = q0 + 320; if (kend > S) kend = S;
    const int nsteps = (kend - kstart) >> 5;   // 10..18, even

    const int lrow = lane >> 2;
    const int swz  = ((lane & 3) ^ ((lane >> 3) & 3)) * 8;  // pre-swizzled granule
    const _Float16* Abase = Pg + (long)qblk * 36864 + (w * 16 + lrow) * 576 + swz;
    const _Float16* Bbase = Vt + (long)(n0 + lrow) * TOK + b * S + kstart + swz;

    auto stage = [&](int bi, int kc) {
        if (w < 4)
            async_load16(Abase + kc, (char*)sA[bi] + w * 1024);
#pragma unroll
        for (int j = 0; j < 2; j++) {
            int g = j * 8 + w;
            async_load16(Bbase + (long)g * 16 * TOK + kc, (char*)sB[bi] + g * 1024);
        }
    };

    const int wm = (w >> 2) * 32;
    const int wn = (w & 3) * 64;
    const int rswz = ((c16 >> 1) & 3);   // == (row>>1)&3 for row = 16*base + c16
    floatx4 acc[2][4] = {};

    stage(0, 0);
    for (int s = 0; s < nsteps; s++) {
        const int bi = s & 1;
        __syncthreads();
        if (s + 1 < nsteps) stage(bi ^ 1, (s + 1) * 32);
        half8 aA[2], bB[4];
#pragma unroll
        for (int mt = 0; mt < 2; mt++)
            aA[mt] = *(const half8*)(sA[bi] + (wm + mt * 16 + c16) * 32 + (quad ^ rswz) * 8);
#pragma unroll
        for (int nt = 0; nt < 4; nt++)
            bB[nt] = *(const half8*)(sB[bi] + (wn + nt * 16 + c16) * 32 + (quad ^ rswz) * 8);
#pragma unroll
        for (int mt = 0; mt < 2; mt++)
#pragma unroll
            for (int nt = 0; nt < 4; nt++)
                acc[mt][nt] = MFMA16(aA[mt], bB[nt], acc[mt][nt]);
    }

    const float* isB = invSum + qblk * 64;
#pragma unroll
    for (int mt = 0; mt < 2; mt++)
#pragma unroll
        for (int nt = 0; nt < 4; nt++)
#pragma unroll
            for (int reg = 0; reg < 4; reg++) {
                int row = wm + mt * 16 + quad * 4 + reg;
                int col = n0 + wn + nt * 16 + c16;
                out[(long)(b * S + q0 + row) * D + col] = acc[mt][nt][reg] * isB[row];
            }
}

extern "C" void kernel_launch(void* const* d_in, const int* in_sizes, int n_in,
                              void* d_out, int out_size, void* d_ws, size_t ws_size,
                              hipStream_t stream) {
    const float* X  = (const float*)d_in[0];
    const float* Y  = (const float*)d_in[1];
    const float* Wq = (const float*)d_in[2];
    const float* Wk = (const float*)d_in[3];
    const float* Wv = (const float*)d_in[4];
    float* out = (float*)d_out;

    const long NTOK = 16384, D = 1024;
    // fp16 workspace. Aliases (all stream-ordered safe):
    //   Kh = Yh   (Yh dead after Q-projection)
    //   Pg,invSum over Xh (Xh dead after V-projection; qk_kernel runs after)
    char* p = (char*)d_ws;
    _Float16* Xh  = (_Float16*)p; p += NTOK * D * 2;   // 32 MB
    _Float16* Yh  = (_Float16*)p; p += NTOK * D * 2;   // 32 MB (reused as Kh)
    _Float16* Wqh = (_Float16*)p; p += D * D * 2;      //  2 MB (pre-scaled by 1/32)
    _Float16* Wkh = (_Float16*)p; p += D * D * 2;
    _Float16* Wvh = (_Float16*)p; p += D * D * 2;
    _Float16* Qh  = (_Float16*)p; p += NTOK * D * 2;   // 32 MB
    _Float16* Vt  = (_Float16*)p; p += NTOK * D * 2;   // 32 MB  [D][NTOK]
    _Float16* Kh  = Yh;
    _Float16* Pg  = Xh;                                // 256*64*576*2 = 18.9 MB
    float* invSum = (float*)(Xh + 256l * 64 * 576);    // 64 KB, still inside Xh

    const int nT = (int)(NTOK * D);
    const int nW = (int)(D * D);
    cvt_kernel<<<nT / 2048, 256, 0, stream>>>(X, Xh, nT, 1.f);
    cvt_kernel<<<nT / 2048, 256, 0, stream>>>(Y, Yh, nT, 1.f);
    cvt_kernel<<<nW / 2048, 256, 0, stream>>>(Wq, Wqh, nW, 0.03125f);  // fold 1/sqrt(1024)
    cvt_kernel<<<nW / 2048, 256, 0, stream>>>(Wk, Wkh, nW, 1.f);
    cvt_kernel<<<nW / 2048, 256, 0, stream>>>(Wv, Wvh, nW, 1.f);

    // Q = Y Wq^T (scaled), K = X Wk^T, Vt = Wv X^T  (256^2 tiles, 8-phase)
    gemm_bt<<<dim3(1024 / 256, 16384 / 256), 512, 0, stream>>>(Yh, Wqh, Qh, 16384, 1024, 1024);
    gemm_bt<<<dim3(1024 / 256, 16384 / 256), 512, 0, stream>>>(Xh, Wkh, Kh, 16384, 1024, 1024);
    gemm_bt<<<dim3(16384 / 256, 1024 / 256), 512, 0, stream>>>(Wvh, Xh, Vt, 1024, 16384, 1024);

    qk_kernel<<<dim3(256), 512, 0, stream>>>(Qh, Kh, Pg, invSum);
    pv_kernel<<<dim3(4 * 256), 512, 0, stream>>>(Pg, invSum, Vt, out);
}